// Round 1
// baseline (1248.558 us; speedup 1.0000x reference)
//
#include <hip/hip_runtime.h>
#include <cstdint>

// B=2 S=2048 HID=2048 H=16 KV=4 D=128, causal GQA + NeoX RoPE, theta=1e4.
// bf16 MFMA (16x16x32) everywhere; fp32 accumulate. Verified gfx950 layouts:
//   A-op: A[m=lane&15][k=quad*8+j] ; B-op: B[k=quad*8+j][n=lane&15]
//   C/D : col=lane&15, row=quad*4+reg

typedef __attribute__((ext_vector_type(8))) short short8;
typedef __attribute__((ext_vector_type(4))) float f32x4;

#define NLOG_THETA_D2 (-0.14391156831212787f) /* -ln(10000)/64 */
#define QSCALE 0.08838834764831845f           /* 1/sqrt(128)   */

__device__ __forceinline__ unsigned short f2bf(float f) {
    unsigned int u = __float_as_uint(f);
    u += 0x7fffu + ((u >> 16) & 1u);   // RNE
    return (unsigned short)(u >> 16);
}

// ---------------- C[M,N] = A[M,K] @ W[K,N] (all fp32 global, bf16 compute) --
__global__ __launch_bounds__(256)
void gemm_kernel(const float* __restrict__ A, const float* __restrict__ W,
                 float* __restrict__ C, int M, int N, int K) {
    __shared__ unsigned short As[128 * 40];  // [m][k], pad 32->40: conflict-free b128
    __shared__ unsigned short Bs[128 * 40];  // [n][k] (transposed in staging)
    const int tid = threadIdx.x;
    const int wid = tid >> 6, lane = tid & 63;
    const int quad = lane >> 4, l16 = lane & 15;
    const int m0 = blockIdx.y * 128, n0 = blockIdx.x * 128;
    const int wm0 = (wid >> 1) * 64, wn0 = (wid & 1) * 64;

    f32x4 acc[4][4] = {};

    for (int k0 = 0; k0 < K; k0 += 32) {
        // stage A tile 128x32
#pragma unroll
        for (int p = 0; p < 4; ++p) {
            int idx = p * 256 + tid;
            int r = idx >> 3, c = (idx & 7) << 2;
            const float4 av = *(const float4*)(A + (size_t)(m0 + r) * K + (k0 + c));
            unsigned int w0 = (unsigned int)f2bf(av.x) | ((unsigned int)f2bf(av.y) << 16);
            unsigned int w1 = (unsigned int)f2bf(av.z) | ((unsigned int)f2bf(av.w) << 16);
            *(uint2*)&As[r * 40 + c] = make_uint2(w0, w1);
        }
        // stage B tile 32x128, transposed to Bs[n][k]
#pragma unroll
        for (int p = 0; p < 4; ++p) {
            int idx = p * 256 + tid;
            int kk = idx >> 5, n = (idx & 31) << 2;
            const float4 wv = *(const float4*)(W + (size_t)(k0 + kk) * N + (n0 + n));
            Bs[(n + 0) * 40 + kk] = f2bf(wv.x);
            Bs[(n + 1) * 40 + kk] = f2bf(wv.y);
            Bs[(n + 2) * 40 + kk] = f2bf(wv.z);
            Bs[(n + 3) * 40 + kk] = f2bf(wv.w);
        }
        __syncthreads();
        short8 a[4], b[4];
#pragma unroll
        for (int i = 0; i < 4; ++i)
            a[i] = *(const short8*)&As[(wm0 + i * 16 + l16) * 40 + quad * 8];
#pragma unroll
        for (int j = 0; j < 4; ++j)
            b[j] = *(const short8*)&Bs[(wn0 + j * 16 + l16) * 40 + quad * 8];
#pragma unroll
        for (int i = 0; i < 4; ++i)
#pragma unroll
            for (int j = 0; j < 4; ++j)
                acc[i][j] = __builtin_amdgcn_mfma_f32_16x16x32_bf16(a[i], b[j], acc[i][j], 0, 0, 0);
        __syncthreads();
    }
#pragma unroll
    for (int i = 0; i < 4; ++i) {
        int rb = m0 + wm0 + i * 16 + quad * 4;
#pragma unroll
        for (int j = 0; j < 4; ++j) {
            int col = n0 + wn0 + j * 16 + l16;
#pragma unroll
            for (int r = 0; r < 4; ++r)
                C[(size_t)(rb + r) * N + col] = acc[i][j][r];
        }
    }
}

// ---------------- flash attention, RoPE fused into Q/K staging -------------
// grid: (S/128, H, B), block 256 (4 waves). BQ=128, BKV=64.
__global__ __launch_bounds__(256)
void attn_kernel(const float* __restrict__ Qg, const float* __restrict__ Kg,
                 const float* __restrict__ Vg, float* __restrict__ Og) {
    // bufA: Q staging [128][136] -> per-tile K [64][136], then P [128][72]
    // bufB: V tile transposed [d=128][kpos 64 +8]
    __shared__ unsigned short bufA[128 * 136]; // 34816 B
    __shared__ unsigned short bufB[128 * 72];  // 18432 B
    const int tid = threadIdx.x;
    const int wid = tid >> 6, lane = tid & 63;
    const int quad = lane >> 4, l16 = lane & 15;
    const int qt = blockIdx.x, h = blockIdx.y, b = blockIdx.z;
    const int kvh = h >> 2;            // H/KV = 4
    const int q0 = qt * 128;
    const int wq0 = wid * 32;          // wave's 32 q-rows
    const int S = 2048, HD = 2048, KVD = 512;

    const int c4 = (tid & 31) << 2;    // column group this thread stages
    const int jf = c4 >> 1;            // rope frequency index (even)
    const float inv1 = expf(NLOG_THETA_D2 * (float)jf);
    const float inv2 = expf(NLOG_THETA_D2 * (float)(jf + 1));

    // ---- stage Q with rope + scale, pull fragments to registers ----
    for (int p = 0; p < 16; ++p) {
        int r = p * 8 + (tid >> 5);
        const float4 xv = *(const float4*)(Qg + (size_t)(b * S + q0 + r) * HD + h * 128 + c4);
        float s1, cc1, s2, cc2;
        float pos = (float)(q0 + r);
        sincosf(pos * inv1, &s1, &cc1);
        sincosf(pos * inv2, &s2, &cc2);
        float o1 = (xv.x * cc1 - xv.y * s1) * QSCALE;   // -> col jf
        float o2 = (xv.z * cc2 - xv.w * s2) * QSCALE;   // -> col jf+1
        float o3 = (xv.x * s1 + xv.y * cc1) * QSCALE;   // -> col 64+jf
        float o4 = (xv.z * s2 + xv.w * cc2) * QSCALE;   // -> col 64+jf+1
        *(unsigned int*)&bufA[r * 136 + jf]      = (unsigned int)f2bf(o1) | ((unsigned int)f2bf(o2) << 16);
        *(unsigned int*)&bufA[r * 136 + 64 + jf] = (unsigned int)f2bf(o3) | ((unsigned int)f2bf(o4) << 16);
    }
    __syncthreads();
    short8 aQ[2][4];
#pragma unroll
    for (int rt = 0; rt < 2; ++rt)
#pragma unroll
        for (int kd = 0; kd < 4; ++kd)
            aQ[rt][kd] = *(const short8*)&bufA[(wq0 + rt * 16 + l16) * 136 + kd * 32 + quad * 8];
    __syncthreads();

    float m_s[2][4], l_s[2][4];
    f32x4 oacc[2][8] = {};
#pragma unroll
    for (int rt = 0; rt < 2; ++rt)
#pragma unroll
        for (int r = 0; r < 4; ++r) { m_s[rt][r] = -1e30f; l_s[rt][r] = 0.f; }

    const int ntiles = 2 * qt + 2;     // kv tiles of 64 up to causal frontier
    for (int kt = 0; kt < ntiles; ++kt) {
        const int kbase = kt * 64;
        // stage K tile [64][136] with rope into bufA
        for (int p = 0; p < 8; ++p) {
            int r = p * 8 + (tid >> 5);
            const float4 kv4 = *(const float4*)(Kg + (size_t)(b * S + kbase + r) * KVD + kvh * 128 + c4);
            float s1, cc1, s2, cc2;
            float pos = (float)(kbase + r);
            sincosf(pos * inv1, &s1, &cc1);
            sincosf(pos * inv2, &s2, &cc2);
            float o1 = kv4.x * cc1 - kv4.y * s1;
            float o2 = kv4.z * cc2 - kv4.w * s2;
            float o3 = kv4.x * s1 + kv4.y * cc1;
            float o4 = kv4.z * s2 + kv4.w * cc2;
            *(unsigned int*)&bufA[r * 136 + jf]      = (unsigned int)f2bf(o1) | ((unsigned int)f2bf(o2) << 16);
            *(unsigned int*)&bufA[r * 136 + 64 + jf] = (unsigned int)f2bf(o3) | ((unsigned int)f2bf(o4) << 16);
        }
        // stage V tile transposed into bufB[d][kpos]
        for (int p = 0; p < 8; ++p) {
            int r = p * 8 + (tid >> 5);
            const float4 vv = *(const float4*)(Vg + (size_t)(b * S + kbase + r) * KVD + kvh * 128 + c4);
            bufB[(c4 + 0) * 72 + r] = f2bf(vv.x);
            bufB[(c4 + 1) * 72 + r] = f2bf(vv.y);
            bufB[(c4 + 2) * 72 + r] = f2bf(vv.z);
            bufB[(c4 + 3) * 72 + r] = f2bf(vv.w);
        }
        __syncthreads();

        // QK^T: scores[32 q-rows][64 kv]
        f32x4 sacc[2][4] = {};
#pragma unroll
        for (int kd = 0; kd < 4; ++kd) {
            short8 bK[4];
#pragma unroll
            for (int ct = 0; ct < 4; ++ct)
                bK[ct] = *(const short8*)&bufA[(ct * 16 + l16) * 136 + kd * 32 + quad * 8];
#pragma unroll
            for (int rt = 0; rt < 2; ++rt)
#pragma unroll
                for (int ct = 0; ct < 4; ++ct)
                    sacc[rt][ct] = __builtin_amdgcn_mfma_f32_16x16x32_bf16(aQ[rt][kd], bK[ct], sacc[rt][ct], 0, 0, 0);
        }
        // causal mask (only near the diagonal)
        if (kbase + 63 > q0) {
#pragma unroll
            for (int rt = 0; rt < 2; ++rt)
#pragma unroll
                for (int ct = 0; ct < 4; ++ct)
#pragma unroll
                    for (int r = 0; r < 4; ++r) {
                        int row = q0 + wq0 + rt * 16 + quad * 4 + r;
                        int col = kbase + ct * 16 + l16;
                        if (col > row) sacc[rt][ct][r] = -1e30f;
                    }
        }
        // online softmax (row state replicated across the 16 lanes of a quad)
        float alph[2][4];
#pragma unroll
        for (int rt = 0; rt < 2; ++rt)
#pragma unroll
            for (int r = 0; r < 4; ++r) {
                float mx = fmaxf(fmaxf(sacc[rt][0][r], sacc[rt][1][r]),
                                 fmaxf(sacc[rt][2][r], sacc[rt][3][r]));
                mx = fmaxf(mx, __shfl_xor(mx, 1, 64));
                mx = fmaxf(mx, __shfl_xor(mx, 2, 64));
                mx = fmaxf(mx, __shfl_xor(mx, 4, 64));
                mx = fmaxf(mx, __shfl_xor(mx, 8, 64));
                float mn = fmaxf(m_s[rt][r], mx);
                float al = expf(m_s[rt][r] - mn);
                m_s[rt][r] = mn;
                float rs = 0.f;
#pragma unroll
                for (int ct = 0; ct < 4; ++ct) {
                    float pv = expf(sacc[rt][ct][r] - mn);
                    sacc[rt][ct][r] = pv;
                    rs += pv;
                }
                rs += __shfl_xor(rs, 1, 64);
                rs += __shfl_xor(rs, 2, 64);
                rs += __shfl_xor(rs, 4, 64);
                rs += __shfl_xor(rs, 8, 64);
                l_s[rt][r] = al * l_s[rt][r] + rs;
                alph[rt][r] = al;
            }
#pragma unroll
        for (int rt = 0; rt < 2; ++rt)
#pragma unroll
            for (int dt = 0; dt < 8; ++dt)
#pragma unroll
                for (int r = 0; r < 4; ++r)
                    oacc[rt][dt][r] *= alph[rt][r];

        __syncthreads();   // everyone done reading K before P overwrites bufA

        // P: C-layout regs -> LDS [qrow][kv] (wave writes only its own rows)
#pragma unroll
        for (int rt = 0; rt < 2; ++rt)
#pragma unroll
            for (int ct = 0; ct < 4; ++ct)
#pragma unroll
                for (int r = 0; r < 4; ++r)
                    bufA[(wq0 + rt * 16 + quad * 4 + r) * 72 + ct * 16 + l16] = f2bf(sacc[rt][ct][r]);
        // PV: O[32 q-rows][128 d] += P @ V
#pragma unroll
        for (int ks = 0; ks < 2; ++ks) {
            short8 aP[2];
#pragma unroll
            for (int rt = 0; rt < 2; ++rt)
                aP[rt] = *(const short8*)&bufA[(wq0 + rt * 16 + l16) * 72 + ks * 32 + quad * 8];
#pragma unroll
            for (int dt = 0; dt < 8; ++dt) {
                short8 bV = *(const short8*)&bufB[(dt * 16 + l16) * 72 + ks * 32 + quad * 8];
#pragma unroll
                for (int rt = 0; rt < 2; ++rt)
                    oacc[rt][dt] = __builtin_amdgcn_mfma_f32_16x16x32_bf16(aP[rt], bV, oacc[rt][dt], 0, 0, 0);
            }
        }
        __syncthreads();   // before next tile's staging
    }

    // epilogue: O /= l, write [b][s][h*128+d]
#pragma unroll
    for (int rt = 0; rt < 2; ++rt)
#pragma unroll
        for (int dt = 0; dt < 8; ++dt)
#pragma unroll
            for (int r = 0; r < 4; ++r) {
                int row = q0 + wq0 + rt * 16 + quad * 4 + r;
                Og[(size_t)(b * S + row) * HD + h * 128 + dt * 16 + l16] =
                    oacc[rt][dt][r] / l_s[rt][r];
            }
}

extern "C" void kernel_launch(void* const* d_in, const int* in_sizes, int n_in,
                              void* d_out, int out_size, void* d_ws, size_t ws_size,
                              hipStream_t stream) {
    const float* x  = (const float*)d_in[0];
    // d_in[1] = mask (causal tril) — implemented analytically
    const float* Wq = (const float*)d_in[2];
    const float* Wk = (const float*)d_in[3];
    const float* Wv = (const float*)d_in[4];
    const float* Wo = (const float*)d_in[5];
    float* out = (float*)d_out;

    float* q  = (float*)d_ws;                       // [4096][2048]
    float* k  = q + (size_t)4096 * 2048;            // [4096][512]
    float* v  = k + (size_t)4096 * 512;             // [4096][512]
    float* ao = v + (size_t)4096 * 512;             // [4096][2048]

    dim3 blk(256);
    gemm_kernel<<<dim3(2048 / 128, 4096 / 128), blk, 0, stream>>>(x, Wq, q, 4096, 2048, 2048);
    gemm_kernel<<<dim3(512 / 128, 4096 / 128), blk, 0, stream>>>(x, Wk, k, 4096, 512, 2048);
    gemm_kernel<<<dim3(512 / 128, 4096 / 128), blk, 0, stream>>>(x, Wv, v, 4096, 512, 2048);
    attn_kernel<<<dim3(2048 / 128, 16, 2), blk, 0, stream>>>(q, k, v, ao);
    gemm_kernel<<<dim3(2048 / 128, 4096 / 128), blk, 0, stream>>>(ao, Wo, out, 4096, 2048, 2048);
}

// Round 2
// 391.412 us; speedup vs baseline: 3.1899x; 3.1899x over previous
//
#include <hip/hip_runtime.h>
#include <cstdint>

// B=2 S=2048 HID=2048 H=16 KV=4 D=128, causal GQA + NeoX RoPE, theta=1e4.
// Pipeline: cvt x->bf16; transpose W->bf16 [N][K]; m97-style bf16 MFMA GEMMs
// (global_load_lds width=16, XOR chunk swizzle => conflict-free ds_read_b128);
// RoPE applied once (prep kernel); V transposed once; flash attention with
// BQ=64, paired q-tiles (z, 31-z) for perfect causal load balance.
// Verified gfx950 layouts: A[m=lane&15][k=quad*8+j]; B[k=quad*8+j][n=lane&15];
// C/D col=lane&15, row=quad*4+reg.

typedef __attribute__((ext_vector_type(8))) short short8;
typedef __attribute__((ext_vector_type(4))) float f32x4;
typedef unsigned short u16;
typedef unsigned int u32;

#define NLOG_THETA_D2 (-0.14391156831212787f) /* -ln(10000)/64 */
#define QSCALE 0.08838834764831845f           /* 1/sqrt(128)   */

__device__ __forceinline__ u16 f2bf(float f) {
    u32 u = __float_as_uint(f);
    u += 0x7fffu + ((u >> 16) & 1u);   // RNE
    return (u16)(u >> 16);
}
__device__ __forceinline__ float bf2f(u16 u) { return __uint_as_float(((u32)u) << 16); }

// async global->LDS, 16 B per lane; LDS dest = wave-uniform base + lane*16
__device__ __forceinline__ void async_copy16(const void* g, void* lds) {
    __builtin_amdgcn_global_load_lds(
        (const __attribute__((address_space(1))) u32*)(uintptr_t)g,
        (__attribute__((address_space(3))) u32*)(uintptr_t)lds, 16, 0, 0);
}

// ---------------- fp32 -> bf16 convert ----------------
__global__ __launch_bounds__(256)
void cvt_bf16_kernel(const float* __restrict__ in, u16* __restrict__ out, int n4) {
    int i = blockIdx.x * 256 + threadIdx.x;
    if (i >= n4) return;
    float4 v = ((const float4*)in)[i];
    ushort4 o;
    o.x = f2bf(v.x); o.y = f2bf(v.y); o.z = f2bf(v.z); o.w = f2bf(v.w);
    ((ushort4*)out)[i] = o;
}

// ---------------- transpose fp32 [R][C] -> bf16 [C][R] (weights) ----------------
__global__ __launch_bounds__(256)
void transpose_f32_bf16(const float* __restrict__ in, u16* __restrict__ out,
                        int R, int C, int orow) {
    __shared__ float tile[32][33];
    int r0 = blockIdx.y * 32, c0 = blockIdx.x * 32;
    int tx = threadIdx.x & 31, ty = threadIdx.x >> 5;
#pragma unroll
    for (int j = 0; j < 4; ++j)
        tile[ty + j * 8][tx] = in[(size_t)(r0 + ty + j * 8) * C + c0 + tx];
    __syncthreads();
#pragma unroll
    for (int j = 0; j < 4; ++j)
        out[(size_t)(orow + c0 + ty + j * 8) * R + r0 + tx] = f2bf(tile[tx][ty + j * 8]);
}

// ---------------- transpose bf16 [R][*inLD] -> bf16 [C][R], batched (V) ----------
__global__ __launch_bounds__(256)
void transpose_bf16(const u16* __restrict__ in, u16* __restrict__ out,
                    int R, int C, int inLD) {
    in  += (size_t)blockIdx.z * R * inLD;
    out += (size_t)blockIdx.z * C * R;
    __shared__ u16 tile[32][33];
    int r0 = blockIdx.y * 32, c0 = blockIdx.x * 32;
    int tx = threadIdx.x & 31, ty = threadIdx.x >> 5;
#pragma unroll
    for (int j = 0; j < 4; ++j)
        tile[ty + j * 8][tx] = in[(size_t)(r0 + ty + j * 8) * inLD + c0 + tx];
    __syncthreads();
#pragma unroll
    for (int j = 0; j < 4; ++j)
        out[(size_t)(c0 + ty + j * 8) * R + r0 + tx] = tile[tx][ty + j * 8];
}

// ---------------- RoPE on q [4096][2048] and k (cols 0..511 of kv [4096][1024]) --
__global__ __launch_bounds__(256)
void rope_qk_kernel(const u16* __restrict__ qB, const u16* __restrict__ kvB,
                    u16* __restrict__ qO, u16* __restrict__ kO) {
    int row = blockIdx.x;                 // b*2048 + s
    float pos = (float)(row & 2047);
    const ushort4* qr = (const ushort4*)(qB + (size_t)row * 2048);
    const ushort4* kr = (const ushort4*)(kvB + (size_t)row * 1024);
    for (int t = threadIdx.x; t < 640; t += 256) {
        ushort4 uv; int c4; u16* ob; float sc;
        if (t < 512) {
            c4 = t * 4; uv = qr[t];
            ob = qO + (size_t)row * 2048 + (c4 & ~127); sc = QSCALE;
        } else {
            int u = t - 512; c4 = u * 4; uv = kr[u];
            ob = kO + (size_t)row * 512 + (c4 & ~127); sc = 1.0f;
        }
        int j = (c4 & 127) >> 1;          // even freq index
        float x0 = bf2f(uv.x), x1 = bf2f(uv.y), x2 = bf2f(uv.z), x3 = bf2f(uv.w);
        float s1, c1, s2, c2;
        sincosf(pos * __expf(NLOG_THETA_D2 * (float)j), &s1, &c1);
        sincosf(pos * __expf(NLOG_THETA_D2 * (float)(j + 1)), &s2, &c2);
        float o1 = (x0 * c1 - x1 * s1) * sc;
        float o2 = (x2 * c2 - x3 * s2) * sc;
        float o3 = (x0 * s1 + x1 * c1) * sc;
        float o4 = (x2 * s2 + x3 * c2) * sc;
        *(u32*)&ob[j]      = (u32)f2bf(o1) | ((u32)f2bf(o2) << 16);
        *(u32*)&ob[64 + j] = (u32)f2bf(o3) | ((u32)f2bf(o4) << 16);
    }
}

// ---------------- C[M,N] = A[M,K](bf16) @ Bt[N,K](bf16)^T, m97 structure --------
template <int OBF>
__global__ __launch_bounds__(256)
void gemm_bf16(const u16* __restrict__ A, const u16* __restrict__ Bt,
               void* __restrict__ Cout, int M, int N, int K) {
    __shared__ __align__(16) u16 As[128 * 32];
    __shared__ __align__(16) u16 Bs[128 * 32];
    const int tid = threadIdx.x, wid = tid >> 6, lane = tid & 63;
    const int quad = lane >> 4, l16 = lane & 15;
    const int m0 = blockIdx.y * 128, n0 = blockIdx.x * 128;
    const int wm0 = (wid >> 1) * 64, wn0 = (wid & 1) * 64;
    f32x4 acc[4][4] = {};

    for (int k0 = 0; k0 < K; k0 += 32) {
        // stage A,B 128x32 via global_load_lds; chunk c' = c ^ ((row>>1)&3)
#pragma unroll
        for (int rr = 0; rr < 2; ++rr) {
            int s = rr * 256 + wid * 64 + lane;
            int row = s >> 2;
            int c = (s & 3) ^ ((row >> 1) & 3);
            async_copy16(A + (size_t)(m0 + row) * K + k0 + c * 8,
                         &As[(size_t)(rr * 256 + wid * 64) * 8]);
            async_copy16(Bt + (size_t)(n0 + row) * K + k0 + c * 8,
                         &Bs[(size_t)(rr * 256 + wid * 64) * 8]);
        }
        __syncthreads();
        short8 a[4], b[4];
#pragma unroll
        for (int i = 0; i < 4; ++i) {
            int ra = wm0 + i * 16 + l16;
            a[i] = *(const short8*)&As[ra * 32 + ((quad ^ ((ra >> 1) & 3)) << 3)];
            int rb = wn0 + i * 16 + l16;
            b[i] = *(const short8*)&Bs[rb * 32 + ((quad ^ ((rb >> 1) & 3)) << 3)];
        }
#pragma unroll
        for (int i = 0; i < 4; ++i)
#pragma unroll
            for (int j = 0; j < 4; ++j)
                acc[i][j] = __builtin_amdgcn_mfma_f32_16x16x32_bf16(a[i], b[j], acc[i][j], 0, 0, 0);
        __syncthreads();
    }
#pragma unroll
    for (int i = 0; i < 4; ++i) {
        int rb = m0 + wm0 + i * 16 + quad * 4;
#pragma unroll
        for (int j = 0; j < 4; ++j) {
            int col = n0 + wn0 + j * 16 + l16;
#pragma unroll
            for (int r = 0; r < 4; ++r) {
                if (OBF) ((u16*)Cout)[(size_t)(rb + r) * N + col] = f2bf(acc[i][j][r]);
                else     ((float*)Cout)[(size_t)(rb + r) * N + col] = acc[i][j][r];
            }
        }
    }
}

// ---------------- flash attention: BQ=64, BKV=64, paired q-tiles ---------------
// grid (16, 16, 2); block 256 (4 waves); block z does q-tiles {z, 31-z} => 33 kv-tiles.
__global__ __launch_bounds__(256)
void attn_kernel(const u16* __restrict__ qb, const u16* __restrict__ kb,
                 const u16* __restrict__ vt, u16* __restrict__ ao) {
    __shared__ __align__(16) u16 bufK[64 * 128];   // 16 KB
    __shared__ __align__(16) u16 bufV[128 * 64];   // 16 KB [d][kv]
    __shared__ __align__(16) u16 bufQP[64 * 128];  // 16 KB: Q stage, then P [64][72]
    const int tid = threadIdx.x, wid = tid >> 6, lane = tid & 63;
    const int quad = lane >> 4, l16 = lane & 15;
    const int z = blockIdx.x, h = blockIdx.y, b = blockIdx.z;
    const int kvh = h >> 2;
    const int wq0 = wid * 16;                      // wave's 16 q-rows
    const u16* qbase = qb + (size_t)b * 2048 * 2048 + h * 128;
    const u16* kbB   = kb + (size_t)b * 2048 * 512 + kvh * 128;
    const u16* vbB   = vt + (size_t)(b * 512 + kvh * 128) * 2048;

    for (int pi = 0; pi < 2; ++pi) {
        const int qt = pi ? (31 - z) : z;
        const int q0 = qt * 64;
        // stage Q [64][128] (16B chunks, c' = c ^ (row&7))
#pragma unroll
        for (int rr = 0; rr < 4; ++rr) {
            int s = rr * 256 + wid * 64 + lane;
            int row = s >> 4, c = (s & 15) ^ (row & 7);
            async_copy16(qbase + (size_t)(q0 + row) * 2048 + c * 8,
                         &bufQP[(size_t)(rr * 256 + wid * 64) * 8]);
        }
        __syncthreads();
        short8 aQ[4];
        {
            int rq = wq0 + l16;
#pragma unroll
            for (int kd = 0; kd < 4; ++kd)
                aQ[kd] = *(const short8*)&bufQP[rq * 128 + (((kd * 4 + quad) ^ (rq & 7)) << 3)];
        }
        float m_s[4] = {-1e30f, -1e30f, -1e30f, -1e30f};
        float l_s[4] = {0.f, 0.f, 0.f, 0.f};
        f32x4 oacc[8] = {};
        const int nt = qt + 1;
        for (int t = 0; t < nt; ++t) {
            const int kk0 = t * 64;
#pragma unroll
            for (int rr = 0; rr < 4; ++rr) {
                int s = rr * 256 + wid * 64 + lane;
                int rK = s >> 4, cK = (s & 15) ^ (rK & 7);
                async_copy16(kbB + (size_t)(kk0 + rK) * 512 + cK * 8,
                             &bufK[(size_t)(rr * 256 + wid * 64) * 8]);
                int rV = s >> 3, cV = (s & 7) ^ (rV & 7);
                async_copy16(vbB + (size_t)rV * 2048 + kk0 + cV * 8,
                             &bufV[(size_t)(rr * 256 + wid * 64) * 8]);
            }
            __syncthreads();
            // S = Q K^T  (16 q-rows x 64 kv per wave)
            f32x4 sacc[4] = {};
#pragma unroll
            for (int kd = 0; kd < 4; ++kd)
#pragma unroll
                for (int ct = 0; ct < 4; ++ct) {
                    int rk = ct * 16 + l16;
                    short8 bK = *(const short8*)&bufK[rk * 128 + (((kd * 4 + quad) ^ (rk & 7)) << 3)];
                    sacc[ct] = __builtin_amdgcn_mfma_f32_16x16x32_bf16(aQ[kd], bK, sacc[ct], 0, 0, 0);
                }
            if (t == qt) {                         // diagonal tile: causal mask
                int rowr = wq0 + quad * 4;
#pragma unroll
                for (int ct = 0; ct < 4; ++ct) {
                    int colr = ct * 16 + l16;
#pragma unroll
                    for (int r = 0; r < 4; ++r)
                        if (colr > rowr + r) sacc[ct][r] = -1e30f;
                }
            }
            // online softmax; row state lives replicated across the 16-lane quad
            float alph[4];
#pragma unroll
            for (int r = 0; r < 4; ++r) {
                float mx = fmaxf(fmaxf(sacc[0][r], sacc[1][r]), fmaxf(sacc[2][r], sacc[3][r]));
                mx = fmaxf(mx, __shfl_xor(mx, 1, 64));
                mx = fmaxf(mx, __shfl_xor(mx, 2, 64));
                mx = fmaxf(mx, __shfl_xor(mx, 4, 64));
                mx = fmaxf(mx, __shfl_xor(mx, 8, 64));
                float mn = fmaxf(m_s[r], mx);
                float al = __expf(m_s[r] - mn);
                m_s[r] = mn;
                float rs = 0.f;
#pragma unroll
                for (int ct = 0; ct < 4; ++ct) {
                    float pv = __expf(sacc[ct][r] - mn);
                    sacc[ct][r] = pv;
                    rs += pv;
                }
                rs += __shfl_xor(rs, 1, 64);
                rs += __shfl_xor(rs, 2, 64);
                rs += __shfl_xor(rs, 4, 64);
                rs += __shfl_xor(rs, 8, 64);
                l_s[r] = al * l_s[r] + rs;
                alph[r] = al;
            }
#pragma unroll
            for (int dt = 0; dt < 8; ++dt)
#pragma unroll
                for (int r = 0; r < 4; ++r)
                    oacc[dt][r] *= alph[r];
            // P C-layout -> LDS A-layout [64][72]; each wave touches only its own rows
#pragma unroll
            for (int ct = 0; ct < 4; ++ct)
#pragma unroll
                for (int r = 0; r < 4; ++r)
                    bufQP[(wq0 + quad * 4 + r) * 72 + ct * 16 + l16] = f2bf(sacc[ct][r]);
            // O += P V
#pragma unroll
            for (int ks = 0; ks < 2; ++ks) {
                short8 aP = *(const short8*)&bufQP[(wq0 + l16) * 72 + ks * 32 + quad * 8];
#pragma unroll
                for (int dt = 0; dt < 8; ++dt) {
                    int rv = dt * 16 + l16;
                    short8 bV = *(const short8*)&bufV[rv * 64 + (((ks * 4 + quad) ^ (rv & 7)) << 3)];
                    oacc[dt] = __builtin_amdgcn_mfma_f32_16x16x32_bf16(aP, bV, oacc[dt], 0, 0, 0);
                }
            }
            __syncthreads();
        }
        float lr[4];
#pragma unroll
        for (int r = 0; r < 4; ++r) lr[r] = 1.0f / l_s[r];
#pragma unroll
        for (int dt = 0; dt < 8; ++dt)
#pragma unroll
            for (int r = 0; r < 4; ++r) {
                int row = b * 2048 + q0 + wq0 + quad * 4 + r;
                ao[(size_t)row * 2048 + h * 128 + dt * 16 + l16] = f2bf(oacc[dt][r] * lr[r]);
            }
    }
}

extern "C" void kernel_launch(void* const* d_in, const int* in_sizes, int n_in,
                              void* d_out, int out_size, void* d_ws, size_t ws_size,
                              hipStream_t stream) {
    const float* x  = (const float*)d_in[0];
    // d_in[1] = causal mask — analytic
    const float* Wq = (const float*)d_in[2];
    const float* Wk = (const float*)d_in[3];
    const float* Wv = (const float*)d_in[4];
    const float* Wo = (const float*)d_in[5];
    float* out = (float*)d_out;

    char* ws = (char*)d_ws;
    u16* WqtWot = (u16*)(ws);               // 8.4 MB: Wqt, later reused for Wot
    u16* Wkvt   = (u16*)(ws + 8388608);     // 4.2 MB: [Wk^T ; Wv^T] = [1024][2048]
    u16* xb_ao  = (u16*)(ws + 12582912);    // 16.8 MB: x bf16, later attn-out bf16
    u16* qB     = (u16*)(ws + 29360128);    // 16.8 MB: q pre-rope bf16
    u16* kvB    = (u16*)(ws + 46137344);    // 8.4 MB: kv pre-rope bf16 [4096][1024]
    u16* qR     = (u16*)(ws + 54525952);    // 16.8 MB: q roped+scaled bf16
    u16* kR     = (u16*)(ws + 71303168);    // 4.2 MB: k roped bf16 [4096][512]
    u16* vT     = (u16*)(ws + 75497472);    // 4.2 MB: v^T bf16 [2][512][2048]
    // total 79,691,776 bytes (< round-1's 84 MB, known to fit)

    dim3 blk(256);
    cvt_bf16_kernel<<<8192, blk, 0, stream>>>(x, xb_ao, 2097152);
    transpose_f32_bf16<<<dim3(64, 64), blk, 0, stream>>>(Wq, WqtWot, 2048, 2048, 0);
    transpose_f32_bf16<<<dim3(16, 64), blk, 0, stream>>>(Wk, Wkvt, 2048, 512, 0);
    transpose_f32_bf16<<<dim3(16, 64), blk, 0, stream>>>(Wv, Wkvt, 2048, 512, 512);
    gemm_bf16<1><<<dim3(16, 32), blk, 0, stream>>>(xb_ao, WqtWot, qB, 4096, 2048, 2048);
    gemm_bf16<1><<<dim3(8, 32), blk, 0, stream>>>(xb_ao, Wkvt, kvB, 4096, 1024, 2048);
    rope_qk_kernel<<<4096, blk, 0, stream>>>(qB, kvB, qR, kR);
    transpose_bf16<<<dim3(16, 64, 2), blk, 0, stream>>>(kvB + 512, vT, 2048, 512, 1024);
    attn_kernel<<<dim3(16, 16, 2), blk, 0, stream>>>(qR, kR, vT, xb_ao);
    transpose_f32_bf16<<<dim3(64, 64), blk, 0, stream>>>(Wo, WqtWot, 2048, 2048, 0);
    gemm_bf16<0><<<dim3(16, 32), blk, 0, stream>>>(xb_ao, WqtWot, out, 4096, 2048, 2048);
}

// Round 4
// 386.292 us; speedup vs baseline: 3.2322x; 1.0133x over previous
//
#include <hip/hip_runtime.h>
#include <cstdint>

// B=2 S=2048 HID=2048 H=16 KV=4 D=128, causal GQA + NeoX RoPE, theta=1e4.
// R4 = R3 with __exp2f -> __builtin_amdgcn_exp2f (glibc macro collision fix).
// Fused QKV GEMM (N=3072); attention around 32x32x16 MFMA with S^T formulation
// (A=K, B=Q^T; O^T = V^T P^T), fixed-shift softmax (exact by shift-invariance),
// P^T built in-register via shfl_xor(32), deferred l-reduction. 5 dispatches.
// Verified layouts: 32x32 C/D: col=lane&31, row=(reg&3)+8*(reg>>2)+4*(lane>>5);
// A[m=lane&31][k=(lane>>5)*8+j]; B[k=(lane>>5)*8+j][n=lane&31].

typedef __attribute__((ext_vector_type(8))) short short8;
typedef __attribute__((ext_vector_type(4))) float f32x4;
typedef __attribute__((ext_vector_type(16))) float f32x16;
typedef unsigned short u16;
typedef unsigned int u32;

#define NLOG_THETA_D2 (-0.14391156831212787f) /* -ln(10000)/64 */
#define QSC_L2E 0.12751779437543f             /* (1/sqrt(128))*log2(e) */
#define M2SHIFT 17.3123404906676f             /* 12*log2(e) */

__device__ __forceinline__ u16 f2bf(float f) {
    u32 u = __float_as_uint(f);
    u += 0x7fffu + ((u >> 16) & 1u);   // RNE
    return (u16)(u >> 16);
}
__device__ __forceinline__ float bf2f(u16 u) { return __uint_as_float(((u32)u) << 16); }
__device__ __forceinline__ float fast_exp2(float x) { return __builtin_amdgcn_exp2f(x); }

__device__ __forceinline__ void async_copy16(const void* g, void* lds) {
    __builtin_amdgcn_global_load_lds(
        (const __attribute__((address_space(1))) u32*)(uintptr_t)g,
        (__attribute__((address_space(3))) u32*)(uintptr_t)lds, 16, 0, 0);
}

// ================= prep: cvt x -> bf16; transpose Wq/Wk/Wv -> Wqkvt ==========
// blocks [0,8192): cvt; [8192,12288): Wq; [12288,13312): Wk; [13312,14336): Wv
__global__ __launch_bounds__(256)
void prep_kernel(const float* __restrict__ x, const float* __restrict__ Wq,
                 const float* __restrict__ Wk, const float* __restrict__ Wv,
                 u16* __restrict__ xb, u16* __restrict__ Wqkvt) {
    __shared__ float tile[32][33];
    int blk = blockIdx.x;
    if (blk < 8192) {
        int i = blk * 256 + threadIdx.x;
        float4 v = ((const float4*)x)[i];
        ushort4 o;
        o.x = f2bf(v.x); o.y = f2bf(v.y); o.z = f2bf(v.z); o.w = f2bf(v.w);
        ((ushort4*)xb)[i] = o;
        return;
    }
    const float* in; int C, orow, bx, by;
    if (blk < 12288)      { int j = blk - 8192;  in = Wq; C = 2048; orow = 0;    bx = j & 63; by = j >> 6; }
    else if (blk < 13312) { int j = blk - 12288; in = Wk; C = 512;  orow = 2048; bx = j & 15; by = j >> 4; }
    else                  { int j = blk - 13312; in = Wv; C = 512;  orow = 2560; bx = j & 15; by = j >> 4; }
    int r0 = by * 32, c0 = bx * 32;
    int tx = threadIdx.x & 31, ty = threadIdx.x >> 5;
#pragma unroll
    for (int j = 0; j < 4; ++j)
        tile[ty + j * 8][tx] = in[(size_t)(r0 + ty + j * 8) * C + c0 + tx];
    __syncthreads();
#pragma unroll
    for (int j = 0; j < 4; ++j)
        Wqkvt[(size_t)(orow + c0 + ty + j * 8) * 2048 + r0 + tx] = f2bf(tile[tx][ty + j * 8]);
}

// ============ rope_vt: RoPE(q,k) + V^T + Wo^T ==============================
// blocks [0,4096): rope rows; [4096,6144): vT; [6144,10240): Wo transpose
__global__ __launch_bounds__(256)
void rope_vt_kernel(const u16* __restrict__ qkv, const float* __restrict__ Wo,
                    u16* __restrict__ qR, u16* __restrict__ kR,
                    u16* __restrict__ vT, u16* __restrict__ Wot) {
    int blk = blockIdx.x;
    if (blk < 4096) {
        int row = blk;                        // b*2048 + s
        float pos = (float)(row & 2047);
        const u16* rbase = qkv + (size_t)row * 3072;
        for (int t = threadIdx.x; t < 640; t += 256) {
            ushort4 uv; int c4; u16* ob; float sc;
            if (t < 512) {
                c4 = t * 4; uv = *(const ushort4*)(rbase + c4);
                ob = qR + (size_t)row * 2048 + (c4 & ~127); sc = QSC_L2E;
            } else {
                int u = t - 512; c4 = u * 4; uv = *(const ushort4*)(rbase + 2048 + c4);
                ob = kR + (size_t)row * 512 + (c4 & ~127); sc = 1.0f;
            }
            int j = (c4 & 127) >> 1;
            float x0 = bf2f(uv.x), x1 = bf2f(uv.y), x2 = bf2f(uv.z), x3 = bf2f(uv.w);
            float s1, c1, s2, c2;
            sincosf(pos * __expf(NLOG_THETA_D2 * (float)j), &s1, &c1);
            sincosf(pos * __expf(NLOG_THETA_D2 * (float)(j + 1)), &s2, &c2);
            float o1 = (x0 * c1 - x1 * s1) * sc;
            float o2 = (x2 * c2 - x3 * s2) * sc;
            float o3 = (x0 * s1 + x1 * c1) * sc;
            float o4 = (x2 * s2 + x3 * c2) * sc;
            *(u32*)&ob[j]      = (u32)f2bf(o1) | ((u32)f2bf(o2) << 16);
            *(u32*)&ob[64 + j] = (u32)f2bf(o3) | ((u32)f2bf(o4) << 16);
        }
        return;
    }
    int tx = threadIdx.x & 31, ty = threadIdx.x >> 5;
    if (blk < 6144) {                          // V slice transpose (bf16)
        __shared__ u16 tile[32][33];
        int j = blk - 4096;
        int b = j >> 10, rem = j & 1023;
        int c0 = (rem & 15) * 32, r0 = (rem >> 4) * 32;
        const u16* in = qkv + (size_t)b * 2048 * 3072 + 2560;
        u16* out = vT + (size_t)b * 512 * 2048;
#pragma unroll
        for (int i = 0; i < 4; ++i)
            tile[ty + i * 8][tx] = in[(size_t)(r0 + ty + i * 8) * 3072 + c0 + tx];
        __syncthreads();
#pragma unroll
        for (int i = 0; i < 4; ++i)
            out[(size_t)(c0 + ty + i * 8) * 2048 + r0 + tx] = tile[tx][ty + i * 8];
        return;
    }
    {                                          // Wo transpose f32->bf16
        __shared__ float tile[32][33];
        int j = blk - 6144;
        int c0 = (j & 63) * 32, r0 = (j >> 6) * 32;
#pragma unroll
        for (int i = 0; i < 4; ++i)
            tile[ty + i * 8][tx] = Wo[(size_t)(r0 + ty + i * 8) * 2048 + c0 + tx];
        __syncthreads();
#pragma unroll
        for (int i = 0; i < 4; ++i)
            Wot[(size_t)(c0 + ty + i * 8) * 2048 + r0 + tx] = f2bf(tile[tx][ty + i * 8]);
    }
}

// ========== C[M,N] = A[M,K](bf16) @ Bt[N,K](bf16)^T, m97 structure ==========
template <int OBF>
__global__ __launch_bounds__(256)
void gemm_bf16(const u16* __restrict__ A, const u16* __restrict__ Bt,
               void* __restrict__ Cout, int M, int N, int K) {
    __shared__ __align__(16) u16 As[128 * 32];
    __shared__ __align__(16) u16 Bs[128 * 32];
    const int tid = threadIdx.x, wid = tid >> 6, lane = tid & 63;
    const int quad = lane >> 4, l16 = lane & 15;
    const int m0 = blockIdx.y * 128, n0 = blockIdx.x * 128;
    const int wm0 = (wid >> 1) * 64, wn0 = (wid & 1) * 64;
    f32x4 acc[4][4] = {};

    for (int k0 = 0; k0 < K; k0 += 32) {
#pragma unroll
        for (int rr = 0; rr < 2; ++rr) {
            int s = rr * 256 + wid * 64 + lane;
            int row = s >> 2;
            int c = (s & 3) ^ ((row >> 1) & 3);
            async_copy16(A + (size_t)(m0 + row) * K + k0 + c * 8,
                         &As[(size_t)(rr * 256 + wid * 64) * 8]);
            async_copy16(Bt + (size_t)(n0 + row) * K + k0 + c * 8,
                         &Bs[(size_t)(rr * 256 + wid * 64) * 8]);
        }
        __syncthreads();
        short8 a[4], b[4];
#pragma unroll
        for (int i = 0; i < 4; ++i) {
            int ra = wm0 + i * 16 + l16;
            a[i] = *(const short8*)&As[ra * 32 + ((quad ^ ((ra >> 1) & 3)) << 3)];
            int rb = wn0 + i * 16 + l16;
            b[i] = *(const short8*)&Bs[rb * 32 + ((quad ^ ((rb >> 1) & 3)) << 3)];
        }
#pragma unroll
        for (int i = 0; i < 4; ++i)
#pragma unroll
            for (int j = 0; j < 4; ++j)
                acc[i][j] = __builtin_amdgcn_mfma_f32_16x16x32_bf16(a[i], b[j], acc[i][j], 0, 0, 0);
        __syncthreads();
    }
#pragma unroll
    for (int i = 0; i < 4; ++i) {
        int rb = m0 + wm0 + i * 16 + quad * 4;
#pragma unroll
        for (int j = 0; j < 4; ++j) {
            int col = n0 + wn0 + j * 16 + l16;
#pragma unroll
            for (int r = 0; r < 4; ++r) {
                if (OBF) ((u16*)Cout)[(size_t)(rb + r) * N + col] = f2bf(acc[i][j][r]);
                else     ((float*)Cout)[(size_t)(rb + r) * N + col] = acc[i][j][r];
            }
        }
    }
}

// ============== flash attention: BQ=128, BKV=64, 32x32x16 MFMA ==============
// grid (16, 16, 2); 4 waves; wave handles 32 q-cols. qt = 15 - blockIdx.x.
__global__ __launch_bounds__(256, 2)
void attn_kernel(const u16* __restrict__ qR, const u16* __restrict__ kR,
                 const u16* __restrict__ vT, u16* __restrict__ ao) {
    __shared__ __align__(16) u16 bufQ[128 * 128];  // 32 KB
    __shared__ __align__(16) u16 bufK[64 * 128];   // 16 KB
    __shared__ __align__(16) u16 bufV[128 * 64];   // 16 KB [d][kv]
    const int tid = threadIdx.x, wid = tid >> 6, lane = tid & 63;
    const int l31 = lane & 31, h = lane >> 5;
    const int qt = 15 - blockIdx.x, hh = blockIdx.y, b = blockIdx.z;
    const int kvh = hh >> 2;
    const int q0 = qt * 128;
    const u16* qB = qR + (size_t)b * 2048 * 2048 + hh * 128;
    const u16* kB = kR + (size_t)b * 2048 * 512 + kvh * 128;
    const u16* vB = vT + (size_t)(b * 512 + kvh * 128) * 2048;

    // stage Q [128][128], chunk swizzle c^(row&7)
#pragma unroll
    for (int rr = 0; rr < 8; ++rr) {
        int s = rr * 256 + wid * 64 + lane;
        int row = s >> 4, c = (s & 15) ^ (row & 7);
        async_copy16(qB + (size_t)(q0 + row) * 2048 + c * 8,
                     &bufQ[(size_t)(rr * 256 + wid * 64) * 8]);
    }
    __syncthreads();
    // Q^T B-frags: lane q = wid*32+l31, k = kd*16 + h*8 + j
    short8 aQ[8];
    const int rq = wid * 32 + l31;
#pragma unroll
    for (int kd = 0; kd < 8; ++kd)
        aQ[kd] = *(const short8*)&bufQ[rq * 128 + (((kd * 2 + h) ^ (rq & 7)) << 3)];

    f32x16 oacc[4] = {};
    float lp = 0.f;
    const int qg = q0 + wid * 32 + l31;      // this lane's q column (global seq)
    const int ntiles = 2 * qt + 2;

    for (int t = 0; t < ntiles; ++t) {
        const int kk0 = t * 64;
#pragma unroll
        for (int rr = 0; rr < 4; ++rr) {
            int s = rr * 256 + wid * 64 + lane;
            int rK = s >> 4, cK = (s & 15) ^ (rK & 7);
            async_copy16(kB + (size_t)(kk0 + rK) * 512 + cK * 8,
                         &bufK[(size_t)(rr * 256 + wid * 64) * 8]);
            int rV = s >> 3, cV = (s & 7) ^ (rV & 7);
            async_copy16(vB + (size_t)rV * 2048 + kk0 + cV * 8,
                         &bufV[(size_t)(rr * 256 + wid * 64) * 8]);
        }
        __syncthreads();

        // S^T[kv][q] = K · Q^T ; m=kv (2 mt of 32), n=q (wave's 32), k=d
        f32x16 sacc[2] = {};
#pragma unroll
        for (int kd = 0; kd < 8; ++kd)
#pragma unroll
            for (int mt = 0; mt < 2; ++mt) {
                int rk = mt * 32 + l31;
                short8 aK = *(const short8*)&bufK[rk * 128 + (((kd * 2 + h) ^ (rk & 7)) << 3)];
                sacc[mt] = __builtin_amdgcn_mfma_f32_32x32x16_bf16(aK, aQ[kd], sacc[mt], 0, 0, 0);
            }

        // exp2 softmax (fixed shift), pack P^T pairs as bf16x2
        u32 pk[2][8];
        const bool domask = (t >= ntiles - 2);
        auto softpack = [&](bool dm) {
#pragma unroll
            for (int mt = 0; mt < 2; ++mt) {
                const int kvb = kk0 + mt * 32 + 4 * h;
#pragma unroll
                for (int p = 0; p < 8; ++p) {
                    int r0 = 2 * p;
                    float s0 = sacc[mt][r0], s1 = sacc[mt][r0 + 1];
                    float p0, p1;
                    if (dm) {
                        int kv0 = kvb + (r0 & 3) + 8 * (r0 >> 2);
                        p0 = (kv0 <= qg)     ? fast_exp2(s0 - M2SHIFT) : 0.f;
                        p1 = (kv0 + 1 <= qg) ? fast_exp2(s1 - M2SHIFT) : 0.f;
                    } else {
                        p0 = fast_exp2(s0 - M2SHIFT);
                        p1 = fast_exp2(s1 - M2SHIFT);
                    }
                    lp += p0 + p1;
                    pk[mt][p] = (u32)f2bf(p0) | ((u32)f2bf(p1) << 16);
                }
            }
        };
        if (domask) softpack(true); else softpack(false);

        // O^T[d][q] += V^T · P^T : A=V^T frags, B=P^T assembled via shfl_xor(32)
#pragma unroll
        for (int ks = 0; ks < 4; ++ks) {
            int mt = ks >> 1, k2 = ks & 1;
            u32 own0 = pk[mt][4 * k2 + 2 * h + 0];
            u32 own1 = pk[mt][4 * k2 + 2 * h + 1];
            u32 snd0 = pk[mt][4 * k2 + 2 * (h ^ 1) + 0];
            u32 snd1 = pk[mt][4 * k2 + 2 * (h ^ 1) + 1];
            u32 rc0 = __shfl_xor((int)snd0, 32, 64);
            u32 rc1 = __shfl_xor((int)snd1, 32, 64);
            union { short8 v; u32 u[4]; } bP;
            bP.u[0] = h ? rc0 : own0;
            bP.u[1] = h ? rc1 : own1;
            bP.u[2] = h ? own0 : rc0;
            bP.u[3] = h ? own1 : rc1;
#pragma unroll
            for (int dt = 0; dt < 4; ++dt) {
                int rv = dt * 32 + l31;
                short8 aV = *(const short8*)&bufV[rv * 64 + (((ks * 2 + h) ^ (rv & 7)) << 3)];
                oacc[dt] = __builtin_amdgcn_mfma_f32_32x32x16_bf16(aV, bP.v, oacc[dt], 0, 0, 0);
            }
        }
        __syncthreads();
    }

    // final l reduction (partner half holds the other 32 kv-rows per column)
    lp += __shfl_xor(lp, 32, 64);
    float linv = 1.0f / lp;
    u16* orow = ao + (size_t)(b * 2048 + qg) * 2048 + hh * 128;
#pragma unroll
    for (int dt = 0; dt < 4; ++dt)
#pragma unroll
        for (int g = 0; g < 4; ++g) {
            ushort4 o4;
            o4.x = f2bf(oacc[dt][4 * g + 0] * linv);
            o4.y = f2bf(oacc[dt][4 * g + 1] * linv);
            o4.z = f2bf(oacc[dt][4 * g + 2] * linv);
            o4.w = f2bf(oacc[dt][4 * g + 3] * linv);
            *(ushort4*)&orow[dt * 32 + 8 * g + 4 * h] = o4;
        }
}

extern "C" void kernel_launch(void* const* d_in, const int* in_sizes, int n_in,
                              void* d_out, int out_size, void* d_ws, size_t ws_size,
                              hipStream_t stream) {
    const float* x  = (const float*)d_in[0];
    // d_in[1] = causal mask — analytic
    const float* Wq = (const float*)d_in[2];
    const float* Wk = (const float*)d_in[3];
    const float* Wv = (const float*)d_in[4];
    const float* Wo = (const float*)d_in[5];
    float* out = (float*)d_out;

    char* ws = (char*)d_ws;
    u16* Wqkvt = (u16*)(ws);                 // [3072][2048] bf16, 12.58 MB
    u16* Wot   = Wqkvt;                      // reuses region after QKV GEMM
    u16* xb_ao = (u16*)(ws + 12582912);      // [4096][2048] bf16 (x, then attn-out)
    u16* qkv   = (u16*)(ws + 29360128);      // [4096][3072] bf16
    u16* qR    = (u16*)(ws + 54525952);      // [4096][2048] bf16 (roped, scaled)
    u16* kR    = (u16*)(ws + 71303168);      // [4096][512] bf16 (roped)
    u16* vT    = (u16*)(ws + 75497472);      // [2][512][2048] bf16
    // total 79,691,776 B

    dim3 blk(256);
    prep_kernel<<<14336, blk, 0, stream>>>(x, Wq, Wk, Wv, xb_ao, Wqkvt);
    gemm_bf16<1><<<dim3(24, 32), blk, 0, stream>>>(xb_ao, Wqkvt, qkv, 4096, 3072, 2048);
    rope_vt_kernel<<<10240, blk, 0, stream>>>(qkv, Wo, qR, kR, vT, Wot);
    attn_kernel<<<dim3(16, 16, 2), blk, 0, stream>>>(qR, kR, vT, xb_ao);
    gemm_bf16<0><<<dim3(16, 32), blk, 0, stream>>>(xb_ao, Wot, out, 4096, 2048, 2048);
}